// Round 1
// 5409.577 us; speedup vs baseline: 1.3054x; 1.3054x over previous
//
#include <hip/hip_runtime.h>

// Dilated 3-layer LSTM, T=512, B=128, D=H=256, rates {1,2,4}.
//
// NEW DESIGN (sync-free scan):
//   prep_kernel : pack Wih/Whh into MFMA B-fragment layout (fp16), fold biases.
//   gx_kernel   : gx[t,n,1024] = x_t @ Wih^T + (bih+bhh), parallel GEMM, output
//                 stored fp16 in MFMA C-fragment order (coalesced both ends).
//   scan_kernel : per block = 16 batch rows x FULL 256 hidden, 8 waves.
//                 h(t-1) exchanged via LDS only -> zero inter-block sync.
//                 Whh fragments: 3/8 register-resident, 5/8 streamed from L2
//                 each step (double-buffered granules under the MFMA stream).
//                 gx prefetched 1 step ahead via global_load_lds; h stores
//                 deferred 1 step so barriers never wait on store-acks.
// Falls back to the previous (verified) ring-sync kernel if ws_size is small.

typedef _Float16 half8   __attribute__((ext_vector_type(8)));
typedef _Float16 half4_t __attribute__((ext_vector_type(4)));
typedef float    floatx4 __attribute__((ext_vector_type(4)));

__device__ __forceinline__ float sigmf(float x) {
    return 1.0f / (1.0f + __expf(-x));
}
__device__ __forceinline__ float tanhfast(float x) {
    float e = __expf(-2.0f * fabsf(x));
    float r = (1.0f - e) / (1.0f + e);
    return copysignf(r, x);
}

#define MFMA16(A, B, C) __builtin_amdgcn_mfma_f32_16x16x32_f16((A), (B), (C), 0, 0, 0)

typedef __attribute__((address_space(3))) unsigned int lds_u32;
typedef __attribute__((address_space(1))) unsigned int glb_u32;

__device__ __forceinline__ void gload_lds16(const _Float16* g, _Float16* l) {
    // per-lane global src, wave-uniform LDS base; lane i lands at base + i*16B
    __builtin_amdgcn_global_load_lds((const glb_u32*)g, (lds_u32*)l, 16, 0, 0);
}

// ---------------------------------------------------------------------------
// prep: pack weights into B-fragment layout + combined bias
// frag(l,w,ct,ks): lane ln holds W[col][k..k+8), col=(ct>>1)*256+w*32+(ct&1)*16+(ln&15),
// k = ks*32 + (ln>>4)*8.  Layout: pack[l][(w*8+ct)*8+ks][ln][8] halves.
// ---------------------------------------------------------------------------
__global__ void prep_kernel(
    const float* __restrict__ Wih, const float* __restrict__ Whh,
    const float* __restrict__ bih, const float* __restrict__ bhh,
    _Float16* __restrict__ wihp, _Float16* __restrict__ whhp,
    float* __restrict__ biasc)
{
    int id = blockIdx.x * 256 + threadIdx.x;
    if (id < 196608) {
        int u = id;
        const float* W = Whh; _Float16* P = whhp;
        if (u >= 98304) { W = Wih; P = wihp; u -= 98304; }
        int ln = u & 63; u >>= 6;
        int ks = u & 7;  u >>= 3;
        int ct = u & 7;  u >>= 3;
        int w  = u & 7;  u >>= 3;
        int l  = u;                                  // 0..2
        int col = (ct >> 1) * 256 + w * 32 + (ct & 1) * 16 + (ln & 15);
        int k0  = ks * 32 + (ln >> 4) * 8;
        const float* src = W + ((size_t)l * 1024 + col) * 256 + k0;
        half8 hv;
#pragma unroll
        for (int j = 0; j < 8; ++j) hv[j] = (_Float16)src[j];
        *(half8*)(P + (size_t)l * 262144 +
                  (size_t)(((w * 8 + ct) * 8 + ks) * 64 + ln) * 8) = hv;
    } else if (id < 199680) {
        int v = id - 196608;                         // 3*1024 combined biases
        biasc[v] = bih[v] + bhh[v];
    }
}

// ---------------------------------------------------------------------------
// gx GEMM: block = 64 packed rows x 1024 gate cols, 8 waves, K=256.
// Output fp16 in C-fragment order: gx[((t*S+sb)*8+w)*4+cp][lane][8halves],
// lane's half8 = {gates ct=2cp (4 rows), gates ct=2cp+1}.
// ---------------------------------------------------------------------------
template<int F16IN>
__global__ __launch_bounds__(512, 2) void gx_kernel(
    const float* __restrict__ in32,
    const _Float16* __restrict__ in16,
    const _Float16* __restrict__ wpack,
    const float* __restrict__ biasc,
    _Float16* __restrict__ gx,
    int rate, int SG, int S)
{
    __shared__ _Float16 Ab[64][264];
    const int tid = threadIdx.x, lane = tid & 63, w = tid >> 6;
    const int t = blockIdx.x / SG, sg = blockIdx.x % SG;
    const int r15 = lane & 15, q = lane >> 4;

#pragma unroll
    for (int i = 0; i < 4; ++i) {
        int id = tid + 512 * i;
        int row = id >> 5, c16 = id & 31;
        int n = sg * 64 + row;
        size_t base = ((size_t)(t * rate + (n >> 7)) * 128 + (n & 127)) * 256 + c16 * 8;
        if (F16IN) {
            *(uint4*)&Ab[row][c16 * 8] = *(const uint4*)(in16 + base);
        } else {
            floatx4 v0 = *(const floatx4*)(in32 + base);
            floatx4 v1 = *(const floatx4*)(in32 + base + 4);
            half8 hv;
            hv[0] = (_Float16)v0[0]; hv[1] = (_Float16)v0[1];
            hv[2] = (_Float16)v0[2]; hv[3] = (_Float16)v0[3];
            hv[4] = (_Float16)v1[0]; hv[5] = (_Float16)v1[1];
            hv[6] = (_Float16)v1[2]; hv[7] = (_Float16)v1[3];
            *(half8*)&Ab[row][c16 * 8] = hv;
        }
    }
    __syncthreads();

    floatx4 zero4 = {0.f, 0.f, 0.f, 0.f};
    floatx4 acc[4][8];
#pragma unroll
    for (int rt = 0; rt < 4; ++rt)
#pragma unroll
        for (int ct = 0; ct < 8; ++ct) acc[rt][ct] = zero4;

    const _Float16* wsp = wpack + (size_t)w * 32768 + (size_t)lane * 8;
    half8 bfA[8], bfB[8];
#pragma unroll
    for (int ct = 0; ct < 8; ++ct)
        bfA[ct] = *(const half8*)(wsp + (ct * 8 + 0) * 512);

#define AKS(ks, bufC, bufN) { \
    if ((ks) + 1 < 8) { _Pragma("unroll") \
        for (int ct = 0; ct < 8; ++ct) \
            bufN[ct] = *(const half8*)(wsp + (ct * 8 + ((ks) + 1)) * 512); } \
    half8 a0 = *(const half8*)&Ab[ 0 + r15][(ks) * 32 + q * 8]; \
    half8 a1 = *(const half8*)&Ab[16 + r15][(ks) * 32 + q * 8]; \
    half8 a2 = *(const half8*)&Ab[32 + r15][(ks) * 32 + q * 8]; \
    half8 a3 = *(const half8*)&Ab[48 + r15][(ks) * 32 + q * 8]; \
    _Pragma("unroll") for (int ct = 0; ct < 8; ++ct) { \
        acc[0][ct] = MFMA16(a0, bufC[ct], acc[0][ct]); \
        acc[1][ct] = MFMA16(a1, bufC[ct], acc[1][ct]); \
        acc[2][ct] = MFMA16(a2, bufC[ct], acc[2][ct]); \
        acc[3][ct] = MFMA16(a3, bufC[ct], acc[3][ct]); } }

    AKS(0, bfA, bfB); AKS(1, bfB, bfA); AKS(2, bfA, bfB); AKS(3, bfB, bfA);
    AKS(4, bfA, bfB); AKS(5, bfB, bfA); AKS(6, bfA, bfB); AKS(7, bfB, bfA);
#undef AKS

    float be[4], bo_[4];
#pragma unroll
    for (int cp = 0; cp < 4; ++cp) {
        be[cp]  = biasc[cp * 256 + w * 32 + r15];
        bo_[cp] = biasc[cp * 256 + w * 32 + 16 + r15];
    }
#pragma unroll
    for (int rt = 0; rt < 4; ++rt) {
        int sb = sg * 4 + rt;
#pragma unroll
        for (int cp = 0; cp < 4; ++cp) {
            half8 hv;
#pragma unroll
            for (int rg = 0; rg < 4; ++rg) {
                hv[rg]     = (_Float16)(acc[rt][2 * cp][rg]     + be[cp]);
                hv[4 + rg] = (_Float16)(acc[rt][2 * cp + 1][rg] + bo_[cp]);
            }
            *(half8*)(gx + ((((size_t)t * S + sb) * 8 + w) * 4 + cp) * 512 +
                      (size_t)lane * 8) = hv;
        }
    }
}

// ---------------------------------------------------------------------------
// scan: grid = S blocks (16 rows each), 8 waves, K=256, zero inter-block sync.
// ---------------------------------------------------------------------------
#define ISSUE(buf, ks) { \
    buf[0] = *(const half8*)(wspi + (3 * 8 + (ks)) * 512); \
    buf[1] = *(const half8*)(wspi + (4 * 8 + (ks)) * 512); \
    buf[2] = *(const half8*)(wspi + (5 * 8 + (ks)) * 512); \
    buf[3] = *(const half8*)(wspi + (6 * 8 + (ks)) * 512); \
    buf[4] = *(const half8*)(wspi + (7 * 8 + (ks)) * 512); }

#define DOKS(ks, buf) { \
    acc[0] = MFMA16(af[ks], rw[0][ks], acc[0]); \
    acc[1] = MFMA16(af[ks], rw[1][ks], acc[1]); \
    acc[2] = MFMA16(af[ks], rw[2][ks], acc[2]); \
    acc[3] = MFMA16(af[ks], buf[0], acc[3]); \
    acc[4] = MFMA16(af[ks], buf[1], acc[4]); \
    acc[5] = MFMA16(af[ks], buf[2], acc[5]); \
    acc[6] = MFMA16(af[ks], buf[3], acc[6]); \
    acc[7] = MFMA16(af[ks], buf[4], acc[7]); }

__global__ __launch_bounds__(512, 2) void scan_kernel(
    const _Float16* __restrict__ gx,
    const _Float16* __restrict__ wpack,
    float* __restrict__ out,
    _Float16* __restrict__ h16,
    int rate, int td, int S)
{
    __shared__ _Float16 Hb[2][16][264];       // h(t) double buffer
    __shared__ _Float16 Gx[8][4][64][8];      // per-wave gx staging

    const int tid  = threadIdx.x;
    const int lane = tid & 63;
    const int w    = tid >> 6;
    const int sb   = blockIdx.x;
    const int r15  = lane & 15;
    const int q    = lane >> 4;

    const _Float16* wsp = wpack + (size_t)w * 32768 + (size_t)lane * 8;

    // register-resident weights: cts 0..2 (96 VGPR)
    half8 rw[3][8];
#pragma unroll
    for (int ct = 0; ct < 3; ++ct)
#pragma unroll
        for (int ks = 0; ks < 8; ++ks)
            rw[ct][ks] = *(const half8*)(wsp + (ct * 8 + ks) * 512);

    for (int i = tid; i < 2 * 16 * 264; i += 512)
        (&Hb[0][0][0])[i] = (_Float16)0.0f;   // h(-1) = 0

    {   // prologue: gx(0) -> LDS (drained by the barrier below)
        const _Float16* g0 = gx + (((size_t)0 * S + sb) * 8 + (size_t)w) * 2048;
#pragma unroll
        for (int cp = 0; cp < 4; ++cp)
            gload_lds16(g0 + cp * 512 + (size_t)lane * 8, &Gx[w][cp][0][0]);
    }
    __syncthreads();

    float cst[8], hprev[8];
#pragma unroll
    for (int i = 0; i < 8; ++i) { cst[i] = 0.f; hprev[i] = 0.f; }

    for (int t = 0; t < td; ++t) {
        const int rd = t & 1, wr = rd ^ 1;

        // defeat LICM so streamed weights are re-fetched (from L2) every step
        const _Float16* wspi = wsp;
        asm volatile("" : "+v"(wspi));

        half8 sA[5], sB[5];
        ISSUE(sA, 0); ISSUE(sB, 1);

        half8 af[8];
#pragma unroll
        for (int ks = 0; ks < 8; ++ks)
            af[ks] = *(const half8*)&Hb[rd][r15][ks * 32 + q * 8];

        floatx4 acc[8];
#pragma unroll
        for (int cp = 0; cp < 4; ++cp) {
            half8 gv = *(const half8*)&Gx[w][cp][lane][0];
#pragma unroll
            for (int rg = 0; rg < 4; ++rg) {
                acc[2 * cp][rg]     = (float)gv[rg];
                acc[2 * cp + 1][rg] = (float)gv[4 + rg];
            }
        }

        DOKS(0, sA); ISSUE(sA, 2);
        DOKS(1, sB); ISSUE(sB, 3);
        DOKS(2, sA); ISSUE(sA, 4);
        DOKS(3, sB); ISSUE(sB, 5);
        DOKS(4, sA); ISSUE(sA, 6);
        DOKS(5, sB); ISSUE(sB, 7);

        {   // prefetch gx(t+1); issued after all stream loads so the counted
            // vmcnt waits for DOKS(6/7) never wait on this HBM access; the
            // end-of-step barrier's vmcnt(0) guarantees it landed.
            int tn = (t + 1 < td) ? (t + 1) : t;
            const _Float16* gn = gx + (((size_t)tn * S + sb) * 8 + (size_t)w) * 2048;
#pragma unroll
            for (int cp = 0; cp < 4; ++cp)
                gload_lds16(gn + cp * 512 + (size_t)lane * 8, &Gx[w][cp][0][0]);
        }

        if (t > 0) {   // deferred global stores of h(t-1); ack hidden by this step
#pragma unroll
            for (int s = 0; s < 2; ++s)
#pragma unroll
                for (int rg = 0; rg < 4; ++rg) {
                    int row = q * 4 + rg, n = sb * 16 + row;
                    int hid = w * 32 + s * 16 + r15;
                    size_t off = ((size_t)((t - 1) * rate + (n >> 7)) * 128 +
                                  (n & 127)) * 256 + hid;
                    float hv = hprev[s * 4 + rg];
                    out[off] = hv;
                    h16[off] = (_Float16)hv;
                }
        }

        DOKS(6, sA);
        DOKS(7, sB);

        // elementwise LSTM cell, fully in-lane (i,f,g,o share lane+reg)
#pragma unroll
        for (int s = 0; s < 2; ++s)
#pragma unroll
            for (int rg = 0; rg < 4; ++rg) {
                int ci = s * 4 + rg;
                float gi = acc[0 + s][rg], gf = acc[2 + s][rg];
                float gg = acc[4 + s][rg], go = acc[6 + s][rg];
                float c = sigmf(gf) * cst[ci] + sigmf(gi) * tanhfast(gg);
                cst[ci] = c;
                float hv = sigmf(go) * tanhfast(c);
                hprev[ci] = hv;
                Hb[wr][q * 4 + rg][w * 32 + s * 16 + r15] = (_Float16)hv;
            }

        __syncthreads();   // orders Hb + drains gx global_load_lds + stores
    }

    // epilogue: store h(td-1)
#pragma unroll
    for (int s = 0; s < 2; ++s)
#pragma unroll
        for (int rg = 0; rg < 4; ++rg) {
            int row = q * 4 + rg, n = sb * 16 + row;
            int hid = w * 32 + s * 16 + r15;
            size_t off = ((size_t)((td - 1) * rate + (n >> 7)) * 128 +
                          (n & 127)) * 256 + hid;
            float hv = hprev[s * 4 + rg];
            out[off] = hv;
            h16[off] = (_Float16)hv;
        }
}

#undef ISSUE
#undef DOKS

// ===========================================================================
// FALLBACK: previous verified kernel (ring + agent-scope sync), used only if
// ws_size cannot hold the gx buffer.
// ===========================================================================
#define GH 16
#define NB 32
#define RING_SLOTS 4
#define RING_STRIDE (512 * 256)
#define RING_BYTES  (RING_SLOTS * RING_STRIDE * 2)
#define CNT_INTS    6144

__global__ __launch_bounds__(256) void lstm_layer_kernel(
    const float* __restrict__ in,
    const float* __restrict__ Wih,
    const float* __restrict__ Whh,
    const float* __restrict__ bih,
    const float* __restrict__ bhh,
    float* __restrict__ out,
    _Float16* __restrict__ ring,
    int* __restrict__ cnt,
    int rate, int td, int G_b)
{
    __shared__ _Float16 Abuf[NB][520];
    __shared__ float scr[NB][68];

    const int tid  = threadIdx.x;
    const int lane = tid & 63;
    const int wv   = tid >> 6;
    const int g_b  = blockIdx.x % G_b;
    const int g_h  = blockIdx.x / G_b;
    const int hid0 = g_h * 16;
    const int n0   = g_b * NB;

    half8 bfrag[16];
    {
        const int col  = lane & 15;
        const int qq   = lane >> 4;
        const int grow = wv * 256 + hid0 + col;
        const float* wih_row = Wih + (size_t)grow * 256;
        const float* whh_row = Whh + (size_t)grow * 256;
#pragma unroll
        for (int ks = 0; ks < 16; ++ks) {
            const int k0 = ks * 32 + qq * 8;
            const float* src = (k0 < 256) ? (wih_row + k0) : (whh_row + (k0 - 256));
            floatx4 w0 = *(const floatx4*)(src);
            floatx4 w1 = *(const floatx4*)(src + 4);
            half8 hb;
            hb[0] = (_Float16)w0[0]; hb[1] = (_Float16)w0[1];
            hb[2] = (_Float16)w0[2]; hb[3] = (_Float16)w0[3];
            hb[4] = (_Float16)w1[0]; hb[5] = (_Float16)w1[1];
            hb[6] = (_Float16)w1[2]; hb[7] = (_Float16)w1[3];
            bfrag[ks] = hb;
        }
    }

    const int erow = tid >> 4;
    const int ehid = tid & 15;
    const float bi = bih[0 * 256 + hid0 + ehid] + bhh[0 * 256 + hid0 + ehid];
    const float bf = bih[1 * 256 + hid0 + ehid] + bhh[1 * 256 + hid0 + ehid];
    const float bg = bih[2 * 256 + hid0 + ehid] + bhh[2 * 256 + hid0 + ehid];
    const float bo = bih[3 * 256 + hid0 + ehid] + bhh[3 * 256 + hid0 + ehid];
    float c0 = 0.0f, c1 = 0.0f;

    floatx4 xp[8];
#pragma unroll
    for (int i = 0; i < 8; ++i) {
        int id  = tid + 256 * i;
        int row = id >> 6;
        int m   = n0 + row;
        const float* p = in + ((size_t)(0 * rate + (m >> 7)) * 128 + (m & 127)) * 256
                         + (size_t)(id & 63) * 4;
        xp[i] = *(const floatx4*)p;
    }

    for (int t = 0; t < td; ++t) {
#pragma unroll
        for (int i = 0; i < 8; ++i) {
            int id  = tid + 256 * i;
            int row = id >> 6;
            int c4  = (id & 63) * 4;
            half4_t hx;
            hx[0] = (_Float16)xp[i][0]; hx[1] = (_Float16)xp[i][1];
            hx[2] = (_Float16)xp[i][2]; hx[3] = (_Float16)xp[i][3];
            *(half4_t*)&Abuf[row][c4] = hx;
        }
        if (t + 1 < td) {
#pragma unroll
            for (int i = 0; i < 8; ++i) {
                int id  = tid + 256 * i;
                int row = id >> 6;
                int m   = n0 + row;
                const float* p = in + ((size_t)((t + 1) * rate + (m >> 7)) * 128 + (m & 127)) * 256
                                 + (size_t)(id & 63) * 4;
                xp[i] = *(const floatx4*)p;
            }
        }
        if (t > 0) {
            const int ci = g_b * td + (t - 1);
            if (tid == 0) {
                while (__hip_atomic_load(&cnt[ci], __ATOMIC_RELAXED,
                                         __HIP_MEMORY_SCOPE_AGENT) < GH) {
                    __builtin_amdgcn_s_sleep(1);
                }
            }
            __syncthreads();
            (void)__hip_atomic_load(&cnt[ci], __ATOMIC_ACQUIRE, __HIP_MEMORY_SCOPE_AGENT);
            const _Float16* rs = ring + (size_t)((t - 1) & 3) * RING_STRIDE;
#pragma unroll
            for (int i = 0; i < 4; ++i) {
                int id  = tid + 256 * i;
                int row = id >> 5;
                int kc  = id & 31;
                int m   = n0 + row;
                uint4 v = *(const uint4*)(rs + (size_t)m * 256 + kc * 8);
                *(uint4*)&Abuf[row][256 + kc * 8] = v;
            }
        } else {
#pragma unroll
            for (int i = 0; i < 4; ++i) {
                int id  = tid + 256 * i;
                int row = id >> 5;
                int kc  = id & 31;
                uint4 z = {0u, 0u, 0u, 0u};
                *(uint4*)&Abuf[row][256 + kc * 8] = z;
            }
        }
        __syncthreads();

        floatx4 acc0 = {0.f, 0.f, 0.f, 0.f};
        floatx4 acc1 = {0.f, 0.f, 0.f, 0.f};
        {
            const int r  = lane & 15;
            const int qq = lane >> 4;
#pragma unroll
            for (int ks = 0; ks < 16; ++ks) {
                half8 a0 = *(const half8*)&Abuf[r][ks * 32 + qq * 8];
                half8 a1 = *(const half8*)&Abuf[16 + r][ks * 32 + qq * 8];
                acc0 = MFMA16(a0, bfrag[ks], acc0);
                acc1 = MFMA16(a1, bfrag[ks], acc1);
            }
        }
        {
            const int r  = lane & 15;
            const int qq = lane >> 4;
#pragma unroll
            for (int reg = 0; reg < 4; ++reg) {
                scr[qq * 4 + reg][wv * 16 + r]      = acc0[reg];
                scr[16 + qq * 4 + reg][wv * 16 + r] = acc1[reg];
            }
        }
        __syncthreads();

        {
            float gi0 = scr[erow][ehid]           + bi;
            float gf0 = scr[erow][16 + ehid]      + bf;
            float gg0 = scr[erow][32 + ehid]      + bg;
            float go0 = scr[erow][48 + ehid]      + bo;
            float gi1 = scr[16 + erow][ehid]      + bi;
            float gf1 = scr[16 + erow][16 + ehid] + bf;
            float gg1 = scr[16 + erow][32 + ehid] + bg;
            float go1 = scr[16 + erow][48 + ehid] + bo;

            c0 = sigmf(gf0) * c0 + sigmf(gi0) * tanhfast(gg0);
            c1 = sigmf(gf1) * c1 + sigmf(gi1) * tanhfast(gg1);
            float h0v = sigmf(go0) * tanhfast(c0);
            float h1v = sigmf(go1) * tanhfast(c1);

            int m0 = n0 + erow, m1 = m0 + 16;
            int tau0 = t * rate + (m0 >> 7);
            int tau1 = t * rate + (m1 >> 7);
            out[((size_t)tau0 * 128 + (m0 & 127)) * 256 + hid0 + ehid] = h0v;
            out[((size_t)tau1 * 128 + (m1 & 127)) * 256 + hid0 + ehid] = h1v;

            _Float16* rw_ = ring + (size_t)(t & 3) * RING_STRIDE;
            rw_[(size_t)m0 * 256 + hid0 + ehid] = (_Float16)h0v;
            rw_[(size_t)m1 * 256 + hid0 + ehid] = (_Float16)h1v;
        }

        __syncthreads();
        if (tid == 0) {
            __hip_atomic_fetch_add(&cnt[g_b * td + t], 1, __ATOMIC_RELEASE,
                                   __HIP_MEMORY_SCOPE_AGENT);
        }
    }
}

// ===========================================================================
extern "C" void kernel_launch(void* const* d_in, const int* in_sizes, int n_in,
                              void* d_out, int out_size, void* d_ws, size_t ws_size,
                              hipStream_t stream) {
    const float* x   = (const float*)d_in[0];
    const float* Wih = (const float*)d_in[1];   // (3, 1024, 256)
    const float* Whh = (const float*)d_in[2];   // (3, 1024, 256)
    const float* bih = (const float*)d_in[3];   // (3, 1024)
    const float* bhh = (const float*)d_in[4];   // (3, 1024)
    float* out = (float*)d_out;                 // (3, 512, 128, 256)

    const size_t GX_BYTES  = 134217728ull;      // 512*128*1024 fp16 (per-layer, reused)
    const size_t H16_BYTES = 33554432ull;       // 512*128*256 fp16
    const size_t WP_BYTES  = 1572864ull;        // 3 * 8*8*8*64*8 fp16
    const size_t NEED = GX_BYTES + H16_BYTES + 2 * WP_BYTES + 12288ull;

    if (ws_size >= NEED) {
        _Float16* gxb  = (_Float16*)d_ws;
        _Float16* h16  = (_Float16*)((char*)d_ws + GX_BYTES);
        _Float16* whhp = (_Float16*)((char*)d_ws + GX_BYTES + H16_BYTES);
        _Float16* wihp = (_Float16*)((char*)d_ws + GX_BYTES + H16_BYTES + WP_BYTES);
        float* biasc   = (float*)((char*)d_ws + GX_BYTES + H16_BYTES + 2 * WP_BYTES);

        prep_kernel<<<dim3(780), dim3(256), 0, stream>>>(
            Wih, Whh, bih, bhh, wihp, whhp, biasc);

        const int rates[3] = {1, 2, 4};
        for (int l = 0; l < 3; ++l) {
            const int rate = rates[l];
            const int td = 512 / rate;
            const int S  = rate * 8;            // blocks of 16 rows
            const int SG = S / 4;
            float* out_l = out + (size_t)l * 512 * 128 * 256;
            if (l == 0)
                gx_kernel<0><<<dim3(td * SG), dim3(512), 0, stream>>>(
                    x, nullptr, wihp + (size_t)l * 262144, biasc + l * 1024,
                    gxb, rate, SG, S);
            else
                gx_kernel<1><<<dim3(td * SG), dim3(512), 0, stream>>>(
                    nullptr, h16, wihp + (size_t)l * 262144, biasc + l * 1024,
                    gxb, rate, SG, S);
            scan_kernel<<<dim3(S), dim3(512), 0, stream>>>(
                gxb, whhp + (size_t)l * 262144, out_l, h16, rate, td, S);
        }
        return;
    }

    // -------- fallback: previous verified path --------
    _Float16* ring = (_Float16*)d_ws;
    int* cnt = (int*)((char*)d_ws + RING_BYTES);
    hipMemsetAsync(cnt, 0, CNT_INTS * sizeof(int), stream);

    const int rates[3]  = {1, 2, 4};
    const int cntOff[3] = {0, 2048, 4096};
    const float* in_ptr = x;
    for (int l = 0; l < 3; ++l) {
        const int rate = rates[l];
        const int td   = 512 / rate;
        const int N    = rate * 128;
        const int G_b  = N / NB;
        lstm_layer_kernel<<<dim3(G_b * GH), dim3(256), 0, stream>>>(
            in_ptr,
            Wih + (size_t)l * 1024 * 256,
            Whh + (size_t)l * 1024 * 256,
            bih + (size_t)l * 1024,
            bhh + (size_t)l * 1024,
            out + (size_t)l * 512 * 128 * 256,
            ring, cnt + cntOff[l],
            rate, td, G_b);
        in_ptr = out + (size_t)l * 512 * 128 * 256;
    }
}

// Round 2
// 5220.859 us; speedup vs baseline: 1.3526x; 1.0361x over previous
//
#include <hip/hip_runtime.h>

// Dilated 3-layer LSTM, T=512, B=128, D=H=256, rates {1,2,4}.
//
// v3: hidden-split x2 block pairs, FULLY register-resident Whh.
//   prep_kernel : pack Wih/Whh into MFMA B-fragment layout (fp16), fold biases.
//   gx_kernel   : gx = x @ Wih^T + bias, parallel GEMM, fp16 C-fragment order.
//   scan2_kernel: block = 16 batch rows x 128 hidden (half), 8 waves.
//                 Whh slice (256KB/block) fully in VGPRs (128/lane) -> zero
//                 per-step weight traffic (the v2 Little's-law wall).
//                 Pair (b, b+NB8) exchanges h halves via L2-local ring +
//                 1 flag bump/poll per step (same-XCD under %8 round-robin).
//                 Sibling half read straight into A-fragments (no staging).
//                 amdgpu_waves_per_eu(2,2) pins the allocator at 256 VGPR
//                 (v2's launch_bounds(512,2) let it target 128 and spill).
// Falls back to the previous verified ring-sync kernel if ws_size is small.

typedef _Float16 half8   __attribute__((ext_vector_type(8)));
typedef _Float16 half4_t __attribute__((ext_vector_type(4)));
typedef float    floatx4 __attribute__((ext_vector_type(4)));

__device__ __forceinline__ float sigmf(float x) {
    return 1.0f / (1.0f + __expf(-x));
}
__device__ __forceinline__ float tanhfast(float x) {
    float e = __expf(-2.0f * fabsf(x));
    float r = (1.0f - e) / (1.0f + e);
    return copysignf(r, x);
}

#define MFMA16(A, B, C) __builtin_amdgcn_mfma_f32_16x16x32_f16((A), (B), (C), 0, 0, 0)

typedef __attribute__((address_space(3))) unsigned int lds_u32;
typedef __attribute__((address_space(1))) unsigned int glb_u32;

__device__ __forceinline__ void gload_lds16(const _Float16* g, _Float16* l) {
    __builtin_amdgcn_global_load_lds((const glb_u32*)g, (lds_u32*)l, 16, 0, 0);
}

#define RING_SLOTS 4
#define RING_STRIDE (512 * 256)    // fp16 elements per ring slot
#define RING_BYTES  (RING_SLOTS * RING_STRIDE * 2)
#define CNT_PER_LAYER 8192
#define CNT_INTS      24576

// ---------------------------------------------------------------------------
// prep: pack weights into B-fragment layout + combined bias
// frag(l,w8,ct8,ks): lane ln holds W[col][k..k+8),
// col=(ct8>>1)*256 + w8*32 + (ct8&1)*16 + (ln&15), k = ks*32 + (ln>>4)*8.
// Layout: pack[l][(w8*8+ct8)*8+ks][ln][8] halves.
// ---------------------------------------------------------------------------
__global__ void prep_kernel(
    const float* __restrict__ Wih, const float* __restrict__ Whh,
    const float* __restrict__ bih, const float* __restrict__ bhh,
    _Float16* __restrict__ wihp, _Float16* __restrict__ whhp,
    float* __restrict__ biasc)
{
    int id = blockIdx.x * 256 + threadIdx.x;
    if (id < 196608) {
        int u = id;
        const float* W = Whh; _Float16* P = whhp;
        if (u >= 98304) { W = Wih; P = wihp; u -= 98304; }
        int ln = u & 63; u >>= 6;
        int ks = u & 7;  u >>= 3;
        int ct = u & 7;  u >>= 3;
        int w  = u & 7;  u >>= 3;
        int l  = u;                                  // 0..2
        int col = (ct >> 1) * 256 + w * 32 + (ct & 1) * 16 + (ln & 15);
        int k0  = ks * 32 + (ln >> 4) * 8;
        const float* src = W + ((size_t)l * 1024 + col) * 256 + k0;
        half8 hv;
#pragma unroll
        for (int j = 0; j < 8; ++j) hv[j] = (_Float16)src[j];
        *(half8*)(P + (size_t)l * 262144 +
                  (size_t)(((w * 8 + ct) * 8 + ks) * 64 + ln) * 8) = hv;
    } else if (id < 199680) {
        int v = id - 196608;                         // 3*1024 combined biases
        biasc[v] = bih[v] + bhh[v];
    }
}

// ---------------------------------------------------------------------------
// gx GEMM: block = 64 packed rows x 1024 gate cols, 8 waves, K=256.
// Output fp16 in C-fragment order: gx[((t*S+sb)*8+w8)*4+cp][lane][8halves],
// lane's half8 = {ct8=2cp rows rg0..3, ct8=2cp+1 rows rg0..3}.
// ---------------------------------------------------------------------------
template<int F16IN>
__global__ __attribute__((amdgpu_flat_work_group_size(512, 512)))
__attribute__((amdgpu_waves_per_eu(2, 2)))
void gx_kernel(
    const float* __restrict__ in32,
    const _Float16* __restrict__ in16,
    const _Float16* __restrict__ wpack,
    const float* __restrict__ biasc,
    _Float16* __restrict__ gx,
    int rate, int SG, int S)
{
    __shared__ _Float16 Ab[64][264];
    const int tid = threadIdx.x, lane = tid & 63, w = tid >> 6;
    const int t = blockIdx.x / SG, sg = blockIdx.x % SG;
    const int r15 = lane & 15, q = lane >> 4;

#pragma unroll
    for (int i = 0; i < 4; ++i) {
        int id = tid + 512 * i;
        int row = id >> 5, c16 = id & 31;
        int n = sg * 64 + row;
        size_t base = ((size_t)(t * rate + (n >> 7)) * 128 + (n & 127)) * 256 + c16 * 8;
        if (F16IN) {
            *(uint4*)&Ab[row][c16 * 8] = *(const uint4*)(in16 + base);
        } else {
            floatx4 v0 = *(const floatx4*)(in32 + base);
            floatx4 v1 = *(const floatx4*)(in32 + base + 4);
            half8 hv;
            hv[0] = (_Float16)v0[0]; hv[1] = (_Float16)v0[1];
            hv[2] = (_Float16)v0[2]; hv[3] = (_Float16)v0[3];
            hv[4] = (_Float16)v1[0]; hv[5] = (_Float16)v1[1];
            hv[6] = (_Float16)v1[2]; hv[7] = (_Float16)v1[3];
            *(half8*)&Ab[row][c16 * 8] = hv;
        }
    }
    __syncthreads();

    floatx4 zero4 = {0.f, 0.f, 0.f, 0.f};
    floatx4 acc[4][8];
#pragma unroll
    for (int rt = 0; rt < 4; ++rt)
#pragma unroll
        for (int ct = 0; ct < 8; ++ct) acc[rt][ct] = zero4;

    const _Float16* wsp = wpack + (size_t)w * 32768 + (size_t)lane * 8;
    half8 bfA[8], bfB[8];
#pragma unroll
    for (int ct = 0; ct < 8; ++ct)
        bfA[ct] = *(const half8*)(wsp + (ct * 8 + 0) * 512);

#define AKS(ks, bufC, bufN) { \
    if ((ks) + 1 < 8) { _Pragma("unroll") \
        for (int ct = 0; ct < 8; ++ct) \
            bufN[ct] = *(const half8*)(wsp + (ct * 8 + ((ks) + 1)) * 512); } \
    half8 a0 = *(const half8*)&Ab[ 0 + r15][(ks) * 32 + q * 8]; \
    half8 a1 = *(const half8*)&Ab[16 + r15][(ks) * 32 + q * 8]; \
    half8 a2 = *(const half8*)&Ab[32 + r15][(ks) * 32 + q * 8]; \
    half8 a3 = *(const half8*)&Ab[48 + r15][(ks) * 32 + q * 8]; \
    _Pragma("unroll") for (int ct = 0; ct < 8; ++ct) { \
        acc[0][ct] = MFMA16(a0, bufC[ct], acc[0][ct]); \
        acc[1][ct] = MFMA16(a1, bufC[ct], acc[1][ct]); \
        acc[2][ct] = MFMA16(a2, bufC[ct], acc[2][ct]); \
        acc[3][ct] = MFMA16(a3, bufC[ct], acc[3][ct]); } }

    AKS(0, bfA, bfB); AKS(1, bfB, bfA); AKS(2, bfA, bfB); AKS(3, bfB, bfA);
    AKS(4, bfA, bfB); AKS(5, bfB, bfA); AKS(6, bfA, bfB); AKS(7, bfB, bfA);
#undef AKS

    float be[4], bo_[4];
#pragma unroll
    for (int cp = 0; cp < 4; ++cp) {
        be[cp]  = biasc[cp * 256 + w * 32 + r15];
        bo_[cp] = biasc[cp * 256 + w * 32 + 16 + r15];
    }
#pragma unroll
    for (int rt = 0; rt < 4; ++rt) {
        int sb = sg * 4 + rt;
#pragma unroll
        for (int cp = 0; cp < 4; ++cp) {
            half8 hv;
#pragma unroll
            for (int rg = 0; rg < 4; ++rg) {
                hv[rg]     = (_Float16)(acc[rt][2 * cp][rg]     + be[cp]);
                hv[4 + rg] = (_Float16)(acc[rt][2 * cp + 1][rg] + bo_[cp]);
            }
            *(half8*)(gx + ((((size_t)t * S + sb) * 8 + w) * 4 + cp) * 512 +
                      (size_t)lane * 8) = hv;
        }
    }
}

// ---------------------------------------------------------------------------
// scan2: grid = 2*NB8 blocks. Block b: bg = b%NB8 (16 batch rows),
// hh = b/NB8 (hidden half). Sibling = (hh^1)*NB8+bg, offset NB8 (mult of 8)
// -> same XCD under round-robin. 8 waves; wave w owns hid w*16..+16 x 4 gates.
// ---------------------------------------------------------------------------
__global__ __attribute__((amdgpu_flat_work_group_size(512, 512)))
__attribute__((amdgpu_waves_per_eu(2, 2)))
void scan2_kernel(
    const _Float16* __restrict__ gx,
    const _Float16* __restrict__ wpack,
    float* __restrict__ out,
    _Float16* __restrict__ h16,
    _Float16* __restrict__ ring,
    int* __restrict__ cnt,
    int rate, int td, int NB8)
{
    __shared__ _Float16 own[2][16][136];     // own h half, padded (+8) dbuf
    __shared__ _Float16 Gx[4][4][64][8];     // gx staging: [chunk a][cp][lane][8]

    const int tid  = threadIdx.x;
    const int lane = tid & 63;
    const int w    = tid >> 6;
    const int r15  = lane & 15;
    const int q    = lane >> 4;
    const int bg   = blockIdx.x % NB8;
    const int hh   = blockIdx.x / NB8;       // 0 or 1
    const int n0   = bg * 16;
    const int myb  = blockIdx.x;
    const int sib  = (hh ^ 1) * NB8 + bg;
    const int hidg = hh * 128 + w * 16 + r15;   // this lane's global hidden idx

    // ---- Whh slice fully register-resident: 32 frags = 128 VGPR ----
    // frag(g,ks) = pack[w8 = hh*4+(w>>1)][ct8 = 2g+(w&1)][ks]
    half8 wf[4][8];
    {
        const int w8 = hh * 4 + (w >> 1), b = w & 1;
#pragma unroll
        for (int g = 0; g < 4; ++g)
#pragma unroll
            for (int ks = 0; ks < 8; ++ks)
                wf[g][ks] = *(const half8*)(wpack +
                    (size_t)(((w8 * 8 + 2 * g + b) * 8 + ks) * 64 + lane) * 8);
    }

    // zero own[0] (h(-1) = 0)
    for (int i = tid; i < 16 * 136; i += 512)
        (&own[0][0][0])[i] = (_Float16)0.0f;

    // prologue: stage gx(0)
#pragma unroll
    for (int j = 0; j < 2; ++j) {
        int gi = w * 2 + j, a = gi >> 2, part = gi & 3;
        const _Float16* src = gx +
            ((((size_t)0 * NB8 + bg) * 8 + (hh * 4 + a)) * 4 + part) * 512 +
            (size_t)lane * 8;
        gload_lds16(src, &Gx[a][part][0][0]);
    }

    float cst[4] = {0.f, 0.f, 0.f, 0.f};
    float hv[4];

    for (int t = 0; t < td; ++t) {
        const int rd = t & 1, wr = rd ^ 1;

        half8 af[8];
        if (t > 0) {
            const int ci = sib * td + (t - 1);
            if (tid == 0) {
                while (__hip_atomic_load(&cnt[ci], __ATOMIC_RELAXED,
                                         __HIP_MEMORY_SCOPE_AGENT) < 1) {
                    __builtin_amdgcn_s_sleep(1);
                }
            }
            __syncthreads();   // barrier A (also drains gx gloads via vmcnt(0))
            (void)__hip_atomic_load(&cnt[ci], __ATOMIC_ACQUIRE,
                                    __HIP_MEMORY_SCOPE_AGENT);
            // sibling h half -> A-fragments directly (L2-local ring read)
            const _Float16* rs = ring + (size_t)((t - 1) & 3) * RING_STRIDE +
                                 (size_t)(n0 + r15) * 256;
            if (hh == 0) {
                af[4] = *(const half8*)(rs + 4 * 32 + q * 8);
                af[5] = *(const half8*)(rs + 5 * 32 + q * 8);
                af[6] = *(const half8*)(rs + 6 * 32 + q * 8);
                af[7] = *(const half8*)(rs + 7 * 32 + q * 8);
            } else {
                af[0] = *(const half8*)(rs + 0 * 32 + q * 8);
                af[1] = *(const half8*)(rs + 1 * 32 + q * 8);
                af[2] = *(const half8*)(rs + 2 * 32 + q * 8);
                af[3] = *(const half8*)(rs + 3 * 32 + q * 8);
            }
        } else {
            __syncthreads();   // barrier A at t=0: drains zeros + gx(0) gloads
            half8 z;
#pragma unroll
            for (int j = 0; j < 8; ++j) z[j] = (_Float16)0.0f;
            if (hh == 0) { af[4] = z; af[5] = z; af[6] = z; af[7] = z; }
            else         { af[0] = z; af[1] = z; af[2] = z; af[3] = z; }
        }

        // acc init from staged gx (bias already folded)
        floatx4 acc[4];
#pragma unroll
        for (int g = 0; g < 4; ++g) {
            half4_t gv = *(const half4_t*)&Gx[w >> 1][g][lane][(w & 1) * 4];
#pragma unroll
            for (int rg = 0; rg < 4; ++rg) acc[g][rg] = (float)gv[rg];
        }

        // own h half -> A-fragments (padded LDS, conflict-free)
        if (hh == 0) {
            af[0] = *(const half8*)&own[rd][r15][0 * 32 + q * 8];
            af[1] = *(const half8*)&own[rd][r15][1 * 32 + q * 8];
            af[2] = *(const half8*)&own[rd][r15][2 * 32 + q * 8];
            af[3] = *(const half8*)&own[rd][r15][3 * 32 + q * 8];
        } else {
            af[4] = *(const half8*)&own[rd][r15][0 * 32 + q * 8];
            af[5] = *(const half8*)&own[rd][r15][1 * 32 + q * 8];
            af[6] = *(const half8*)&own[rd][r15][2 * 32 + q * 8];
            af[7] = *(const half8*)&own[rd][r15][3 * 32 + q * 8];
        }

#define DO_KS(ks) { \
        acc[0] = MFMA16(af[ks], wf[0][ks], acc[0]); \
        acc[1] = MFMA16(af[ks], wf[1][ks], acc[1]); \
        acc[2] = MFMA16(af[ks], wf[2][ks], acc[2]); \
        acc[3] = MFMA16(af[ks], wf[3][ks], acc[3]); }
        if (hh == 0) {   // own ks first (LDS-fast), sibling ks after (L2 loads)
            DO_KS(0) DO_KS(1) DO_KS(2) DO_KS(3)
            DO_KS(4) DO_KS(5) DO_KS(6) DO_KS(7)
        } else {
            DO_KS(4) DO_KS(5) DO_KS(6) DO_KS(7)
            DO_KS(0) DO_KS(1) DO_KS(2) DO_KS(3)
        }
#undef DO_KS

        // elementwise LSTM cell: lane owns rows q*4+rg, hidden hidg
        _Float16* rngw = ring + (size_t)(t & 3) * RING_STRIDE;
#pragma unroll
        for (int rg = 0; rg < 4; ++rg) {
            float gi = acc[0][rg], gf = acc[1][rg];
            float gg = acc[2][rg], go = acc[3][rg];
            float c = sigmf(gf) * cst[rg] + sigmf(gi) * tanhfast(gg);
            cst[rg] = c;
            float h = sigmf(go) * tanhfast(c);
            hv[rg] = h;
            own[wr][q * 4 + rg][w * 16 + r15] = (_Float16)h;
            rngw[(size_t)(n0 + q * 4 + rg) * 256 + hidg] = (_Float16)h;
        }

        __syncthreads();   // barrier B: all ring stores + own ds_writes drained
        if (tid == 0) {
            __hip_atomic_fetch_add(&cnt[myb * td + t], 1, __ATOMIC_RELEASE,
                                   __HIP_MEMORY_SCOPE_AGENT);
        }

        // deferred (off critical path): out fp32 + h16 fp16 stores
#pragma unroll
        for (int rg = 0; rg < 4; ++rg) {
            int n = n0 + q * 4 + rg;
            int tau = t * rate + (n >> 7);
            size_t off = ((size_t)tau * 128 + (n & 127)) * 256 + hidg;
            out[off] = hv[rg];
            h16[off] = (_Float16)hv[rg];
        }

        // prefetch gx(t+1) (issued after B so barrier-A vmcnt(0) drains it)
        if (t + 1 < td) {
#pragma unroll
            for (int j = 0; j < 2; ++j) {
                int gi = w * 2 + j, a = gi >> 2, part = gi & 3;
                const _Float16* src = gx +
                    ((((size_t)(t + 1) * NB8 + bg) * 8 + (hh * 4 + a)) * 4 + part) * 512 +
                    (size_t)lane * 8;
                gload_lds16(src, &Gx[a][part][0][0]);
            }
        }
    }
}

// ===========================================================================
// FALLBACK: original verified kernel (ring + 16-way agent-scope sync), used
// only if ws_size cannot hold the gx buffer.
// ===========================================================================
#define GH 16
#define NB 32
#define FB_CNT_INTS 6144

__global__ __launch_bounds__(256) void lstm_layer_kernel(
    const float* __restrict__ in,
    const float* __restrict__ Wih,
    const float* __restrict__ Whh,
    const float* __restrict__ bih,
    const float* __restrict__ bhh,
    float* __restrict__ out,
    _Float16* __restrict__ ring,
    int* __restrict__ cnt,
    int rate, int td, int G_b)
{
    __shared__ _Float16 Abuf[NB][520];
    __shared__ float scr[NB][68];

    const int tid  = threadIdx.x;
    const int lane = tid & 63;
    const int wv   = tid >> 6;
    const int g_b  = blockIdx.x % G_b;
    const int g_h  = blockIdx.x / G_b;
    const int hid0 = g_h * 16;
    const int n0   = g_b * NB;

    half8 bfrag[16];
    {
        const int col  = lane & 15;
        const int qq   = lane >> 4;
        const int grow = wv * 256 + hid0 + col;
        const float* wih_row = Wih + (size_t)grow * 256;
        const float* whh_row = Whh + (size_t)grow * 256;
#pragma unroll
        for (int ks = 0; ks < 16; ++ks) {
            const int k0 = ks * 32 + qq * 8;
            const float* src = (k0 < 256) ? (wih_row + k0) : (whh_row + (k0 - 256));
            floatx4 w0 = *(const floatx4*)(src);
            floatx4 w1 = *(const floatx4*)(src + 4);
            half8 hb;
            hb[0] = (_Float16)w0[0]; hb[1] = (_Float16)w0[1];
            hb[2] = (_Float16)w0[2]; hb[3] = (_Float16)w0[3];
            hb[4] = (_Float16)w1[0]; hb[5] = (_Float16)w1[1];
            hb[6] = (_Float16)w1[2]; hb[7] = (_Float16)w1[3];
            bfrag[ks] = hb;
        }
    }

    const int erow = tid >> 4;
    const int ehid = tid & 15;
    const float bi = bih[0 * 256 + hid0 + ehid] + bhh[0 * 256 + hid0 + ehid];
    const float bf = bih[1 * 256 + hid0 + ehid] + bhh[1 * 256 + hid0 + ehid];
    const float bg = bih[2 * 256 + hid0 + ehid] + bhh[2 * 256 + hid0 + ehid];
    const float bo = bih[3 * 256 + hid0 + ehid] + bhh[3 * 256 + hid0 + ehid];
    float c0 = 0.0f, c1 = 0.0f;

    floatx4 xp[8];
#pragma unroll
    for (int i = 0; i < 8; ++i) {
        int id  = tid + 256 * i;
        int row = id >> 6;
        int m   = n0 + row;
        const float* p = in + ((size_t)(0 * rate + (m >> 7)) * 128 + (m & 127)) * 256
                         + (size_t)(id & 63) * 4;
        xp[i] = *(const floatx4*)p;
    }

    for (int t = 0; t < td; ++t) {
#pragma unroll
        for (int i = 0; i < 8; ++i) {
            int id  = tid + 256 * i;
            int row = id >> 6;
            int c4  = (id & 63) * 4;
            half4_t hx;
            hx[0] = (_Float16)xp[i][0]; hx[1] = (_Float16)xp[i][1];
            hx[2] = (_Float16)xp[i][2]; hx[3] = (_Float16)xp[i][3];
            *(half4_t*)&Abuf[row][c4] = hx;
        }
        if (t + 1 < td) {
#pragma unroll
            for (int i = 0; i < 8; ++i) {
                int id  = tid + 256 * i;
                int row = id >> 6;
                int m   = n0 + row;
                const float* p = in + ((size_t)((t + 1) * rate + (m >> 7)) * 128 + (m & 127)) * 256
                                 + (size_t)(id & 63) * 4;
                xp[i] = *(const floatx4*)p;
            }
        }
        if (t > 0) {
            const int ci = g_b * td + (t - 1);
            if (tid == 0) {
                while (__hip_atomic_load(&cnt[ci], __ATOMIC_RELAXED,
                                         __HIP_MEMORY_SCOPE_AGENT) < GH) {
                    __builtin_amdgcn_s_sleep(1);
                }
            }
            __syncthreads();
            (void)__hip_atomic_load(&cnt[ci], __ATOMIC_ACQUIRE, __HIP_MEMORY_SCOPE_AGENT);
            const _Float16* rs = ring + (size_t)((t - 1) & 3) * RING_STRIDE;
#pragma unroll
            for (int i = 0; i < 4; ++i) {
                int id  = tid + 256 * i;
                int row = id >> 5;
                int kc  = id & 31;
                int m   = n0 + row;
                uint4 v = *(const uint4*)(rs + (size_t)m * 256 + kc * 8);
                *(uint4*)&Abuf[row][256 + kc * 8] = v;
            }
        } else {
#pragma unroll
            for (int i = 0; i < 4; ++i) {
                int id  = tid + 256 * i;
                int row = id >> 5;
                int kc  = id & 31;
                uint4 z = {0u, 0u, 0u, 0u};
                *(uint4*)&Abuf[row][256 + kc * 8] = z;
            }
        }
        __syncthreads();

        floatx4 acc0 = {0.f, 0.f, 0.f, 0.f};
        floatx4 acc1 = {0.f, 0.f, 0.f, 0.f};
        {
            const int r  = lane & 15;
            const int qq = lane >> 4;
#pragma unroll
            for (int ks = 0; ks < 16; ++ks) {
                half8 a0 = *(const half8*)&Abuf[r][ks * 32 + qq * 8];
                half8 a1 = *(const half8*)&Abuf[16 + r][ks * 32 + qq * 8];
                acc0 = MFMA16(a0, bfrag[ks], acc0);
                acc1 = MFMA16(a1, bfrag[ks], acc1);
            }
        }
        {
            const int r  = lane & 15;
            const int qq = lane >> 4;
#pragma unroll
            for (int reg = 0; reg < 4; ++reg) {
                scr[qq * 4 + reg][wv * 16 + r]      = acc0[reg];
                scr[16 + qq * 4 + reg][wv * 16 + r] = acc1[reg];
            }
        }
        __syncthreads();

        {
            float gi0 = scr[erow][ehid]           + bi;
            float gf0 = scr[erow][16 + ehid]      + bf;
            float gg0 = scr[erow][32 + ehid]      + bg;
            float go0 = scr[erow][48 + ehid]      + bo;
            float gi1 = scr[16 + erow][ehid]      + bi;
            float gf1 = scr[16 + erow][16 + ehid] + bf;
            float gg1 = scr[16 + erow][32 + ehid] + bg;
            float go1 = scr[16 + erow][48 + ehid] + bo;

            c0 = sigmf(gf0) * c0 + sigmf(gi0) * tanhfast(gg0);
            c1 = sigmf(gf1) * c1 + sigmf(gi1) * tanhfast(gg1);
            float h0v = sigmf(go0) * tanhfast(c0);
            float h1v = sigmf(go1) * tanhfast(c1);

            int m0 = n0 + erow, m1 = m0 + 16;
            int tau0 = t * rate + (m0 >> 7);
            int tau1 = t * rate + (m1 >> 7);
            out[((size_t)tau0 * 128 + (m0 & 127)) * 256 + hid0 + ehid] = h0v;
            out[((size_t)tau1 * 128 + (m1 & 127)) * 256 + hid0 + ehid] = h1v;

            _Float16* rw_ = ring + (size_t)(t & 3) * RING_STRIDE;
            rw_[(size_t)m0 * 256 + hid0 + ehid] = (_Float16)h0v;
            rw_[(size_t)m1 * 256 + hid0 + ehid] = (_Float16)h1v;
        }

        __syncthreads();
        if (tid == 0) {
            __hip_atomic_fetch_add(&cnt[g_b * td + t], 1, __ATOMIC_RELEASE,
                                   __HIP_MEMORY_SCOPE_AGENT);
        }
    }
}

// ===========================================================================
extern "C" void kernel_launch(void* const* d_in, const int* in_sizes, int n_in,
                              void* d_out, int out_size, void* d_ws, size_t ws_size,
                              hipStream_t stream) {
    const float* x   = (const float*)d_in[0];
    const float* Wih = (const float*)d_in[1];   // (3, 1024, 256)
    const float* Whh = (const float*)d_in[2];   // (3, 1024, 256)
    const float* bih = (const float*)d_in[3];   // (3, 1024)
    const float* bhh = (const float*)d_in[4];   // (3, 1024)
    float* out = (float*)d_out;                 // (3, 512, 128, 256)

    const size_t GX_BYTES   = 134217728ull;     // 512*128*1024 fp16
    const size_t H16_BYTES  = 33554432ull;      // 512*128*256 fp16
    const size_t WP_BYTES   = 1572864ull;       // 3 * 64*8*64*8 fp16
    const size_t BIAS_BYTES = 12288ull;
    const size_t NEED = GX_BYTES + H16_BYTES + 2 * WP_BYTES + BIAS_BYTES +
                        RING_BYTES + CNT_INTS * sizeof(int);

    if (ws_size >= NEED) {
        char* p = (char*)d_ws;
        _Float16* gxb  = (_Float16*)p;                 p += GX_BYTES;
        _Float16* h16  = (_Float16*)p;                 p += H16_BYTES;
        _Float16* whhp = (_Float16*)p;                 p += WP_BYTES;
        _Float16* wihp = (_Float16*)p;                 p += WP_BYTES;
        float*    biasc= (float*)p;                    p += BIAS_BYTES;
        _Float16* ring = (_Float16*)p;                 p += RING_BYTES;
        int*      cnt  = (int*)p;

        hipMemsetAsync(cnt, 0, CNT_INTS * sizeof(int), stream);
        prep_kernel<<<dim3(780), dim3(256), 0, stream>>>(
            Wih, Whh, bih, bhh, wihp, whhp, biasc);

        const int rates[3] = {1, 2, 4};
        for (int l = 0; l < 3; ++l) {
            const int rate = rates[l];
            const int td   = 512 / rate;
            const int NB8  = rate * 8;          // 16-row batch groups
            const int SG   = NB8 / 4;
            float* out_l = out + (size_t)l * 512 * 128 * 256;
            if (l == 0)
                gx_kernel<0><<<dim3(td * SG), dim3(512), 0, stream>>>(
                    x, nullptr, wihp + (size_t)l * 262144, biasc + l * 1024,
                    gxb, rate, SG, NB8);
            else
                gx_kernel<1><<<dim3(td * SG), dim3(512), 0, stream>>>(
                    nullptr, h16, wihp + (size_t)l * 262144, biasc + l * 1024,
                    gxb, rate, SG, NB8);
            scan2_kernel<<<dim3(2 * NB8), dim3(512), 0, stream>>>(
                gxb, whhp + (size_t)l * 262144, out_l, h16, ring,
                cnt + l * CNT_PER_LAYER, rate, td, NB8);
        }
        return;
    }

    // -------- fallback: original verified path --------
    _Float16* ring = (_Float16*)d_ws;
    int* cnt = (int*)((char*)d_ws + RING_BYTES);
    hipMemsetAsync(cnt, 0, FB_CNT_INTS * sizeof(int), stream);

    const int rates[3]  = {1, 2, 4};
    const int cntOff[3] = {0, 2048, 4096};
    const float* in_ptr = x;
    for (int l = 0; l < 3; ++l) {
        const int rate = rates[l];
        const int td   = 512 / rate;
        const int N    = rate * 128;
        const int G_b  = N / NB;
        lstm_layer_kernel<<<dim3(G_b * GH), dim3(256), 0, stream>>>(
            in_ptr,
            Wih + (size_t)l * 1024 * 256,
            Whh + (size_t)l * 1024 * 256,
            bih + (size_t)l * 1024,
            bhh + (size_t)l * 1024,
            out + (size_t)l * 512 * 128 * 256,
            ring, cnt + cntOff[l],
            rate, td, G_b);
        in_ptr = out + (size_t)l * 512 * 128 * 256;
    }
}

// Round 3
// 4614.544 us; speedup vs baseline: 1.5304x; 1.1314x over previous
//
#include <hip/hip_runtime.h>

// Dilated 3-layer LSTM, T=512, B=128, D=H=256, rates {1,2,4}.
//
// v4: 4-way hidden split, 4-wave blocks, TRULY register-resident Whh.
//   prep_kernel : pack Wih/Whh into MFMA B-fragment layout (fp16), fold biases.
//   gx_kernel   : gx = x @ Wih^T + bias, parallel GEMM, fp16 C-fragment order.
//                 Rewritten with acc[4][2] (~100 VGPR) - v3's 215-reg version
//                 was spilling at the 128-reg allocator cap.
//   scan4_kernel: block = 16 batch rows x 64 hidden, 4 waves (256 thr).
//                 __launch_bounds__(256,1) -> 1 wave/SIMD -> 512-VGPR budget;
//                 Whh quarter (128 KB) = 128 VGPR/lane, pinned with asm so the
//                 allocator cannot rematerialize the loads (v2/v3 failure).
//                 4-sibling exchange: per-block counters, 3 parallel pollers
//                 (waves 0-2), h(t-1) staged to LDS via global_load_lds with
//                 XOR source pre-swizzle; gx prefetched straight to registers.
// Falls back to the original verified ring-sync kernel if ws_size is small.

typedef _Float16 half8   __attribute__((ext_vector_type(8)));
typedef _Float16 half4_t __attribute__((ext_vector_type(4)));
typedef float    floatx4 __attribute__((ext_vector_type(4)));

__device__ __forceinline__ float sigmf(float x) {
    return 1.0f / (1.0f + __expf(-x));
}
__device__ __forceinline__ float tanhfast(float x) {
    float e = __expf(-2.0f * fabsf(x));
    float r = (1.0f - e) / (1.0f + e);
    return copysignf(r, x);
}

#define MFMA16(A, B, C) __builtin_amdgcn_mfma_f32_16x16x32_f16((A), (B), (C), 0, 0, 0)

typedef __attribute__((address_space(3))) unsigned int lds_u32;
typedef __attribute__((address_space(1))) unsigned int glb_u32;

__device__ __forceinline__ void gload_lds16(const _Float16* g, _Float16* l) {
    // per-lane global src (include lane offset in g), wave-uniform LDS base;
    // lane i lands at base + i*16B
    __builtin_amdgcn_global_load_lds((const glb_u32*)g, (lds_u32*)l, 16, 0, 0);
}

#define RING_STRIDE (512 * 256)        // fp16 elements per ring slot (max N=512)
#define BR_SLOTS    2                  // big-path ring slots (2 is provably safe)
#define BR_RING_BYTES (BR_SLOTS * RING_STRIDE * 2)
#define CNT_PER_LAYER 16384
#define CNT_INTS      49152

// ---------------------------------------------------------------------------
// prep: pack weights into B-fragment layout + combined bias
// frag(l,w8,ct8,ks): lane ln holds W[col][k..k+8),
// col=(ct8>>1)*256 + w8*32 + (ct8&1)*16 + (ln&15), k = ks*32 + (ln>>4)*8.
// Layout: pack[l][(w8*8+ct8)*8+ks][ln][8] halves.  (gate = ct8>>1, i,f,g,o)
// ---------------------------------------------------------------------------
__global__ void prep_kernel(
    const float* __restrict__ Wih, const float* __restrict__ Whh,
    const float* __restrict__ bih, const float* __restrict__ bhh,
    _Float16* __restrict__ wihp, _Float16* __restrict__ whhp,
    float* __restrict__ biasc)
{
    int id = blockIdx.x * 256 + threadIdx.x;
    if (id < 196608) {
        int u = id;
        const float* W = Whh; _Float16* P = whhp;
        if (u >= 98304) { W = Wih; P = wihp; u -= 98304; }
        int ln = u & 63; u >>= 6;
        int ks = u & 7;  u >>= 3;
        int ct = u & 7;  u >>= 3;
        int w  = u & 7;  u >>= 3;
        int l  = u;                                  // 0..2
        int col = (ct >> 1) * 256 + w * 32 + (ct & 1) * 16 + (ln & 15);
        int k0  = ks * 32 + (ln >> 4) * 8;
        const float* src = W + ((size_t)l * 1024 + col) * 256 + k0;
        half8 hv;
#pragma unroll
        for (int j = 0; j < 8; ++j) hv[j] = (_Float16)src[j];
        *(half8*)(P + (size_t)l * 262144 +
                  (size_t)(((w * 8 + ct) * 8 + ks) * 64 + ln) * 8) = hv;
    } else if (id < 199680) {
        int v = id - 196608;                         // 3*1024 combined biases
        biasc[v] = bih[v] + bhh[v];
    }
}

// ---------------------------------------------------------------------------
// gx GEMM: block = 64 packed rows x 256 gate cols (one w8-pair), 8 waves.
// wave w: w8 = 2*cb + (w&1), gate cp = w>>1, parities j=0,1; acc[4 rt][2 j].
// Output fp16 C-fragment order: gx[((t*NB8+bg)*8+w8)*4+cp][lane][8],
// hv[rg]=parity0 rows q*4+rg, hv[4+rg]=parity1.
// ---------------------------------------------------------------------------
template<int F16IN>
__global__ __launch_bounds__(512, 1) void gx_kernel(
    const float* __restrict__ in32,
    const _Float16* __restrict__ in16,
    const _Float16* __restrict__ wpack,   // layer slice
    const float* __restrict__ biasc,      // layer slice (1024)
    _Float16* __restrict__ gx,
    int rate, int RB, int NB8)
{
    __shared__ _Float16 Ab[64][264];
    const int tid = threadIdx.x, lane = tid & 63, w = tid >> 6;
    const int cb  = blockIdx.x & 3;
    const int nbi = (blockIdx.x >> 2) % RB;
    const int t   = (blockIdx.x >> 2) / RB;
    const int r15 = lane & 15, q = lane >> 4;
    const int w8  = 2 * cb + (w & 1);
    const int cp  = w >> 1;

    // stage A tile: 64 rows x 256 k (fp16)
#pragma unroll
    for (int i = 0; i < 4; ++i) {
        int id = tid + 512 * i;
        int row = id >> 5, c16 = id & 31;
        int n = nbi * 64 + row;
        size_t base = ((size_t)(t * rate + (n >> 7)) * 128 + (n & 127)) * 256 + c16 * 8;
        if (F16IN) {
            *(uint4*)&Ab[row][c16 * 8] = *(const uint4*)(in16 + base);
        } else {
            floatx4 v0 = *(const floatx4*)(in32 + base);
            floatx4 v1 = *(const floatx4*)(in32 + base + 4);
            half8 hv;
            hv[0] = (_Float16)v0[0]; hv[1] = (_Float16)v0[1];
            hv[2] = (_Float16)v0[2]; hv[3] = (_Float16)v0[3];
            hv[4] = (_Float16)v1[0]; hv[5] = (_Float16)v1[1];
            hv[6] = (_Float16)v1[2]; hv[7] = (_Float16)v1[3];
            *(half8*)&Ab[row][c16 * 8] = hv;
        }
    }
    __syncthreads();

    floatx4 zero4 = {0.f, 0.f, 0.f, 0.f};
    floatx4 acc[4][2];
#pragma unroll
    for (int rt = 0; rt < 4; ++rt) { acc[rt][0] = zero4; acc[rt][1] = zero4; }

    const _Float16* wb = wpack + (size_t)((w8 * 8 + 2 * cp) * 8) * 512 +
                         (size_t)lane * 8;
#pragma unroll
    for (int ks = 0; ks < 8; ++ks) {
        half8 bf0 = *(const half8*)(wb + (size_t)(0 * 8 + ks) * 512);
        half8 bf1 = *(const half8*)(wb + (size_t)(1 * 8 + ks) * 512);
        half8 a0 = *(const half8*)&Ab[ 0 + r15][ks * 32 + q * 8];
        half8 a1 = *(const half8*)&Ab[16 + r15][ks * 32 + q * 8];
        half8 a2 = *(const half8*)&Ab[32 + r15][ks * 32 + q * 8];
        half8 a3 = *(const half8*)&Ab[48 + r15][ks * 32 + q * 8];
        acc[0][0] = MFMA16(a0, bf0, acc[0][0]); acc[0][1] = MFMA16(a0, bf1, acc[0][1]);
        acc[1][0] = MFMA16(a1, bf0, acc[1][0]); acc[1][1] = MFMA16(a1, bf1, acc[1][1]);
        acc[2][0] = MFMA16(a2, bf0, acc[2][0]); acc[2][1] = MFMA16(a2, bf1, acc[2][1]);
        acc[3][0] = MFMA16(a3, bf0, acc[3][0]); acc[3][1] = MFMA16(a3, bf1, acc[3][1]);
    }

    const float be0 = biasc[cp * 256 + w8 * 32 + r15];
    const float be1 = biasc[cp * 256 + w8 * 32 + 16 + r15];
#pragma unroll
    for (int rt = 0; rt < 4; ++rt) {
        int bg = nbi * 4 + rt;
        half8 hv;
#pragma unroll
        for (int rg = 0; rg < 4; ++rg) {
            hv[rg]     = (_Float16)(acc[rt][0][rg] + be0);
            hv[4 + rg] = (_Float16)(acc[rt][1][rg] + be1);
        }
        *(half8*)(gx + ((((size_t)t * NB8 + bg) * 8 + w8) * 4 + cp) * 512 +
                  (size_t)lane * 8) = hv;
    }
}

// ---------------------------------------------------------------------------
// scan4: grid = 4*NB8 blocks of 256 threads (4 waves).
// Block b: bg = b%NB8 (16 batch rows), hb = b/NB8 (hidden quarter).
// Wave wv = gate (i,f,g,o); per wave 4 hid-tiles x 8 ks = 32 B-frags in VGPRs.
// Siblings {s*NB8+bg} (stride = mult of 8 -> same XCD round-robin).
// ---------------------------------------------------------------------------
__global__ __launch_bounds__(256, 1) void scan4_kernel(
    const _Float16* __restrict__ gx,
    const _Float16* __restrict__ wpack,   // layer slice of whhp
    float* __restrict__ out,
    _Float16* __restrict__ h16,
    _Float16* __restrict__ ring,
    int* __restrict__ cnt,                // layer slice
    int rate, int td, int NB8)
{
    __shared__ _Float16 Hs[4096];         // h(t-1): 16 rows x 256, XOR-swizzled
    __shared__ float scr[16][260];        // gates scratch [row][gate*64+hid]

    const int tid  = threadIdx.x;
    const int lane = tid & 63;
    const int wv   = tid >> 6;            // wave = gate 0..3
    const int r15  = lane & 15;
    const int q    = lane >> 4;
    const int bg   = blockIdx.x % NB8;
    const int hb   = blockIdx.x / NB8;    // hidden quarter 0..3
    const int n0   = bg * 16;
    const int myb  = blockIdx.x;

    // ---- Whh quarter-slice -> registers (32 frags = 128 VGPR), asm-pinned ----
    const _Float16* wsl = wpack + (size_t)(2 * hb) * 64 * 512;
    half8 wf[4][8];
#pragma unroll
    for (int ht = 0; ht < 4; ++ht) {
        const int ct8 = 2 * wv + (ht & 1);
        const int w8r = ht >> 1;
#pragma unroll
        for (int ks = 0; ks < 8; ++ks) {
            wf[ht][ks] = *(const half8*)(wsl +
                (size_t)(((w8r * 8 + ct8) * 8 + ks) * 64 + lane) * 8);
            asm volatile("" : "+v"(wf[ht][ks]));   // non-rematerializable
        }
    }

    float cst[4] = {0.f, 0.f, 0.f, 0.f};

    // gx(0) -> registers (each wave needs exactly 2 half8s)
    half8 gxc[2];
#pragma unroll
    for (int w8r = 0; w8r < 2; ++w8r)
        gxc[w8r] = *(const half8*)(gx +
            ((((size_t)0 * NB8 + bg) * 8 + (2 * hb + w8r)) * 4 + wv) * 512 +
            (size_t)lane * 8);

    for (int t = 0; t < td; ++t) {
        // ---- sync with siblings + stage h(t-1) into LDS ----
        if (t > 0) {
            if ((tid & 63) == 0 && wv < 3) {       // 3 parallel pollers
                int s = wv + (wv >= hb ? 1 : 0);   // sibling quarter != hb
                const int ci = (s * NB8 + bg) * td + (t - 1);
                while (__hip_atomic_load(&cnt[ci], __ATOMIC_RELAXED,
                                         __HIP_MEMORY_SCOPE_AGENT) < 1)
                    __builtin_amdgcn_s_sleep(1);
            }
            __syncthreads();                                   // A
            (void)__hip_atomic_load(&cnt[myb * td + (t - 1)], __ATOMIC_ACQUIRE,
                                    __HIP_MEMORY_SCOPE_AGENT);
            const _Float16* rs = ring + (size_t)((t - 1) & 1) * RING_STRIDE +
                                 (size_t)n0 * 256;
#pragma unroll
            for (int jj = 0; jj < 2; ++jj) {
                int c = wv * 2 + jj;               // 1KB chunk (2 rows)
                int D = c * 1024 + lane * 16;      // linear LDS dest byte
                int row = D >> 9;
                int O = D ^ ((row & 7) << 4);      // inverse swizzle on source
                gload_lds16(rs + (O >> 1), Hs + c * 512);
            }
        } else {
            __syncthreads();
            uint4 z = {0u, 0u, 0u, 0u};
            *(uint4*)((char*)Hs + tid * 32)      = z;          // h(-1)=0
            *(uint4*)((char*)Hs + tid * 32 + 16) = z;
        }
        __syncthreads();                                       // A2 (drains)

        // ---- A-frags (swizzled read) + acc init from gx regs ----
        half8 af[8];
#pragma unroll
        for (int ks = 0; ks < 8; ++ks) {
            const int bo = r15 * 512 + ((ks * 64 + q * 16) ^ ((r15 & 7) << 4));
            af[ks] = *(const half8*)((const char*)Hs + bo);
        }
        floatx4 acc[4];
#pragma unroll
        for (int ht = 0; ht < 4; ++ht)
#pragma unroll
            for (int rg = 0; rg < 4; ++rg)
                acc[ht][rg] = (float)gxc[ht >> 1][(ht & 1) * 4 + rg];

#pragma unroll
        for (int ks = 0; ks < 8; ++ks) {
            acc[0] = MFMA16(af[ks], wf[0][ks], acc[0]);
            acc[1] = MFMA16(af[ks], wf[1][ks], acc[1]);
            acc[2] = MFMA16(af[ks], wf[2][ks], acc[2]);
            acc[3] = MFMA16(af[ks], wf[3][ks], acc[3]);
        }

        // ---- gate exchange via scr ----
#pragma unroll
        for (int ht = 0; ht < 4; ++ht)
#pragma unroll
            for (int rg = 0; rg < 4; ++rg)
                scr[q * 4 + rg][wv * 64 + ht * 16 + r15] = acc[ht][rg];
        __syncthreads();                                       // C

        // ---- cell: 4 cells/thread, fully vectorized reads ----
        {
            const int row  = tid >> 4;
            const int hid4 = (tid & 15) * 4;
            floatx4 gi = *(const floatx4*)&scr[row][  0 + hid4];
            floatx4 gf = *(const floatx4*)&scr[row][ 64 + hid4];
            floatx4 gg = *(const floatx4*)&scr[row][128 + hid4];
            floatx4 go = *(const floatx4*)&scr[row][192 + hid4];
            floatx4 ov; half4_t hh;
#pragma unroll
            for (int c2 = 0; c2 < 4; ++c2) {
                float cc = sigmf(gf[c2]) * cst[c2] + sigmf(gi[c2]) * tanhfast(gg[c2]);
                cst[c2] = cc;
                float h = sigmf(go[c2]) * tanhfast(cc);
                ov[c2] = h; hh[c2] = (_Float16)h;
            }
            const int n    = n0 + row;
            const int tau  = t * rate + (n >> 7);
            const int hidg = hb * 64 + hid4;
            size_t off = ((size_t)tau * 128 + (n & 127)) * 256 + hidg;
            *(floatx4*)(out + off) = ov;
            *(half4_t*)(h16 + off) = hh;
            _Float16* rw_ = ring + (size_t)(t & 1) * RING_STRIDE;
            *(half4_t*)(rw_ + (size_t)n * 256 + hidg) = hh;
        }

        __syncthreads();                                       // B (drain stores)
        if (tid == 0)
            __hip_atomic_fetch_add(&cnt[myb * td + t], 1, __ATOMIC_RELEASE,
                                   __HIP_MEMORY_SCOPE_AGENT);

        // ---- prefetch gx(t+1) straight to registers (drained at next A) ----
        {
            const int tn = (t + 1 < td) ? (t + 1) : t;
#pragma unroll
            for (int w8r = 0; w8r < 2; ++w8r)
                gxc[w8r] = *(const half8*)(gx +
                    ((((size_t)tn * NB8 + bg) * 8 + (2 * hb + w8r)) * 4 + wv) * 512 +
                    (size_t)lane * 8);
        }
    }
}

// ===========================================================================
// FALLBACK: original verified kernel (ring + 16-way agent-scope sync), used
// only if ws_size cannot hold the gx buffer.
// ===========================================================================
#define GH 16
#define NB 32
#define FB_RING_SLOTS 4
#define FB_RING_BYTES (FB_RING_SLOTS * RING_STRIDE * 2)
#define FB_CNT_INTS 6144

__global__ __launch_bounds__(256) void lstm_layer_kernel(
    const float* __restrict__ in,
    const float* __restrict__ Wih,
    const float* __restrict__ Whh,
    const float* __restrict__ bih,
    const float* __restrict__ bhh,
    float* __restrict__ out,
    _Float16* __restrict__ ring,
    int* __restrict__ cnt,
    int rate, int td, int G_b)
{
    __shared__ _Float16 Abuf[NB][520];
    __shared__ float scr[NB][68];

    const int tid  = threadIdx.x;
    const int lane = tid & 63;
    const int wv   = tid >> 6;
    const int g_b  = blockIdx.x % G_b;
    const int g_h  = blockIdx.x / G_b;
    const int hid0 = g_h * 16;
    const int n0   = g_b * NB;

    half8 bfrag[16];
    {
        const int col  = lane & 15;
        const int qq   = lane >> 4;
        const int grow = wv * 256 + hid0 + col;
        const float* wih_row = Wih + (size_t)grow * 256;
        const float* whh_row = Whh + (size_t)grow * 256;
#pragma unroll
        for (int ks = 0; ks < 16; ++ks) {
            const int k0 = ks * 32 + qq * 8;
            const float* src = (k0 < 256) ? (wih_row + k0) : (whh_row + (k0 - 256));
            floatx4 w0 = *(const floatx4*)(src);
            floatx4 w1 = *(const floatx4*)(src + 4);
            half8 hb;
            hb[0] = (_Float16)w0[0]; hb[1] = (_Float16)w0[1];
            hb[2] = (_Float16)w0[2]; hb[3] = (_Float16)w0[3];
            hb[4] = (_Float16)w1[0]; hb[5] = (_Float16)w1[1];
            hb[6] = (_Float16)w1[2]; hb[7] = (_Float16)w1[3];
            bfrag[ks] = hb;
        }
    }

    const int erow = tid >> 4;
    const int ehid = tid & 15;
    const float bi = bih[0 * 256 + hid0 + ehid] + bhh[0 * 256 + hid0 + ehid];
    const float bf = bih[1 * 256 + hid0 + ehid] + bhh[1 * 256 + hid0 + ehid];
    const float bg = bih[2 * 256 + hid0 + ehid] + bhh[2 * 256 + hid0 + ehid];
    const float bo = bih[3 * 256 + hid0 + ehid] + bhh[3 * 256 + hid0 + ehid];
    float c0 = 0.0f, c1 = 0.0f;

    floatx4 xp[8];
#pragma unroll
    for (int i = 0; i < 8; ++i) {
        int id  = tid + 256 * i;
        int row = id >> 6;
        int m   = n0 + row;
        const float* p = in + ((size_t)(0 * rate + (m >> 7)) * 128 + (m & 127)) * 256
                         + (size_t)(id & 63) * 4;
        xp[i] = *(const floatx4*)p;
    }

    for (int t = 0; t < td; ++t) {
#pragma unroll
        for (int i = 0; i < 8; ++i) {
            int id  = tid + 256 * i;
            int row = id >> 6;
            int c4  = (id & 63) * 4;
            half4_t hx;
            hx[0] = (_Float16)xp[i][0]; hx[1] = (_Float16)xp[i][1];
            hx[2] = (_Float16)xp[i][2]; hx[3] = (_Float16)xp[i][3];
            *(half4_t*)&Abuf[row][c4] = hx;
        }
        if (t + 1 < td) {
#pragma unroll
            for (int i = 0; i < 8; ++i) {
                int id  = tid + 256 * i;
                int row = id >> 6;
                int m   = n0 + row;
                const float* p = in + ((size_t)((t + 1) * rate + (m >> 7)) * 128 + (m & 127)) * 256
                                 + (size_t)(id & 63) * 4;
                xp[i] = *(const floatx4*)p;
            }
        }
        if (t > 0) {
            const int ci = g_b * td + (t - 1);
            if (tid == 0) {
                while (__hip_atomic_load(&cnt[ci], __ATOMIC_RELAXED,
                                         __HIP_MEMORY_SCOPE_AGENT) < GH) {
                    __builtin_amdgcn_s_sleep(1);
                }
            }
            __syncthreads();
            (void)__hip_atomic_load(&cnt[ci], __ATOMIC_ACQUIRE, __HIP_MEMORY_SCOPE_AGENT);
            const _Float16* rs = ring + (size_t)((t - 1) & 3) * RING_STRIDE;
#pragma unroll
            for (int i = 0; i < 4; ++i) {
                int id  = tid + 256 * i;
                int row = id >> 5;
                int kc  = id & 31;
                int m   = n0 + row;
                uint4 v = *(const uint4*)(rs + (size_t)m * 256 + kc * 8);
                *(uint4*)&Abuf[row][256 + kc * 8] = v;
            }
        } else {
#pragma unroll
            for (int i = 0; i < 4; ++i) {
                int id  = tid + 256 * i;
                int row = id >> 5;
                int kc  = id & 31;
                uint4 z = {0u, 0u, 0u, 0u};
                *(uint4*)&Abuf[row][256 + kc * 8] = z;
            }
        }
        __syncthreads();

        floatx4 acc0 = {0.f, 0.f, 0.f, 0.f};
        floatx4 acc1 = {0.f, 0.f, 0.f, 0.f};
        {
            const int r  = lane & 15;
            const int qq = lane >> 4;
#pragma unroll
            for (int ks = 0; ks < 16; ++ks) {
                half8 a0 = *(const half8*)&Abuf[r][ks * 32 + qq * 8];
                half8 a1 = *(const half8*)&Abuf[16 + r][ks * 32 + qq * 8];
                acc0 = MFMA16(a0, bfrag[ks], acc0);
                acc1 = MFMA16(a1, bfrag[ks], acc1);
            }
        }
        {
            const int r  = lane & 15;
            const int qq = lane >> 4;
#pragma unroll
            for (int reg = 0; reg < 4; ++reg) {
                scr[qq * 4 + reg][wv * 16 + r]      = acc0[reg];
                scr[16 + qq * 4 + reg][wv * 16 + r] = acc1[reg];
            }
        }
        __syncthreads();

        {
            float gi0 = scr[erow][ehid]           + bi;
            float gf0 = scr[erow][16 + ehid]      + bf;
            float gg0 = scr[erow][32 + ehid]      + bg;
            float go0 = scr[erow][48 + ehid]      + bo;
            float gi1 = scr[16 + erow][ehid]      + bi;
            float gf1 = scr[16 + erow][16 + ehid] + bf;
            float gg1 = scr[16 + erow][32 + ehid] + bg;
            float go1 = scr[16 + erow][48 + ehid] + bo;

            c0 = sigmf(gf0) * c0 + sigmf(gi0) * tanhfast(gg0);
            c1 = sigmf(gf1) * c1 + sigmf(gi1) * tanhfast(gg1);
            float h0v = sigmf(go0) * tanhfast(c0);
            float h1v = sigmf(go1) * tanhfast(c1);

            int m0 = n0 + erow, m1 = m0 + 16;
            int tau0 = t * rate + (m0 >> 7);
            int tau1 = t * rate + (m1 >> 7);
            out[((size_t)tau0 * 128 + (m0 & 127)) * 256 + hid0 + ehid] = h0v;
            out[((size_t)tau1 * 128 + (m1 & 127)) * 256 + hid0 + ehid] = h1v;

            _Float16* rw_ = ring + (size_t)(t & 3) * RING_STRIDE;
            rw_[(size_t)m0 * 256 + hid0 + ehid] = (_Float16)h0v;
            rw_[(size_t)m1 * 256 + hid0 + ehid] = (_Float16)h1v;
        }

        __syncthreads();
        if (tid == 0) {
            __hip_atomic_fetch_add(&cnt[g_b * td + t], 1, __ATOMIC_RELEASE,
                                   __HIP_MEMORY_SCOPE_AGENT);
        }
    }
}

// ===========================================================================
extern "C" void kernel_launch(void* const* d_in, const int* in_sizes, int n_in,
                              void* d_out, int out_size, void* d_ws, size_t ws_size,
                              hipStream_t stream) {
    const float* x   = (const float*)d_in[0];
    const float* Wih = (const float*)d_in[1];   // (3, 1024, 256)
    const float* Whh = (const float*)d_in[2];   // (3, 1024, 256)
    const float* bih = (const float*)d_in[3];   // (3, 1024)
    const float* bhh = (const float*)d_in[4];   // (3, 1024)
    float* out = (float*)d_out;                 // (3, 512, 128, 256)

    const size_t GX_BYTES   = 134217728ull;     // 512*128*1024 fp16
    const size_t H16_BYTES  = 33554432ull;      // 512*128*256 fp16
    const size_t WP_BYTES   = 1572864ull;       // per packed array (3 layers)
    const size_t BIAS_BYTES = 12288ull;
    const size_t NEED = GX_BYTES + H16_BYTES + 2 * WP_BYTES + BIAS_BYTES +
                        BR_RING_BYTES + (size_t)CNT_INTS * 4;

    if (ws_size >= NEED) {
        char* p = (char*)d_ws;
        _Float16* gxb   = (_Float16*)p;                p += GX_BYTES;
        _Float16* h16   = (_Float16*)p;                p += H16_BYTES;
        _Float16* whhp  = (_Float16*)p;                p += WP_BYTES;
        _Float16* wihp  = (_Float16*)p;                p += WP_BYTES;
        float*    biasc = (float*)p;                   p += BIAS_BYTES;
        _Float16* ring  = (_Float16*)p;                p += BR_RING_BYTES;
        int*      cnt   = (int*)p;

        hipMemsetAsync(cnt, 0, (size_t)CNT_INTS * 4, stream);
        prep_kernel<<<dim3(780), dim3(256), 0, stream>>>(
            Wih, Whh, bih, bhh, wihp, whhp, biasc);

        const int rates[3] = {1, 2, 4};
        for (int l = 0; l < 3; ++l) {
            const int rate = rates[l];
            const int td   = 512 / rate;
            const int NB8  = rate * 8;          // 16-row batch groups
            const int RB   = rate * 2;          // 64-row blocks per t
            float* out_l = out + (size_t)l * 512 * 128 * 256;
            if (l == 0)
                gx_kernel<0><<<dim3(td * RB * 4), dim3(512), 0, stream>>>(
                    x, nullptr, wihp + (size_t)l * 262144, biasc + l * 1024,
                    gxb, rate, RB, NB8);
            else
                gx_kernel<1><<<dim3(td * RB * 4), dim3(512), 0, stream>>>(
                    nullptr, h16, wihp + (size_t)l * 262144, biasc + l * 1024,
                    gxb, rate, RB, NB8);
            scan4_kernel<<<dim3(4 * NB8), dim3(256), 0, stream>>>(
                gxb, whhp + (size_t)l * 262144, out_l, h16, ring,
                cnt + l * CNT_PER_LAYER, rate, td, NB8);
        }
        return;
    }

    // -------- fallback: original verified path --------
    _Float16* ring = (_Float16*)d_ws;
    int* cnt = (int*)((char*)d_ws + FB_RING_BYTES);
    hipMemsetAsync(cnt, 0, FB_CNT_INTS * sizeof(int), stream);

    const int rates[3]  = {1, 2, 4};
    const int cntOff[3] = {0, 2048, 4096};
    const float* in_ptr = x;
    for (int l = 0; l < 3; ++l) {
        const int rate = rates[l];
        const int td   = 512 / rate;
        const int N    = rate * 128;
        const int G_b  = N / NB;
        lstm_layer_kernel<<<dim3(G_b * GH), dim3(256), 0, stream>>>(
            in_ptr,
            Wih + (size_t)l * 1024 * 256,
            Whh + (size_t)l * 1024 * 256,
            bih + (size_t)l * 1024,
            bhh + (size_t)l * 1024,
            out + (size_t)l * 512 * 128 * 256,
            ring, cnt + cntOff[l],
            rate, td, G_b);
        in_ptr = out + (size_t)l * 512 * 128 * 256;
    }
}